// Round 7
// baseline (654.701 us; speedup 1.0000x reference)
//
#include <hip/hip_runtime.h>
#include <cstdint>
#include <cstddef>

typedef short short8 __attribute__((ext_vector_type(8)));
typedef float f32x4 __attribute__((ext_vector_type(4)));
typedef int   i32x4 __attribute__((ext_vector_type(4)));

#define NPATCH 262144
#define NBAGS  32
#define IN_DIM 1024
#define F_DIM  256
#define A_DIM  128
#define ROWSB  128                 // rows per block (4 waves x 32 rows)
#define NBLK   (NPATCH / ROWSB)    // 2048

__device__ __forceinline__ unsigned short f2bf(float f){
  uint32_t u = __builtin_bit_cast(uint32_t, f);
  u += 0x7fffu + ((u >> 16) & 1u);
  return (unsigned short)(u >> 16);
}
__device__ __forceinline__ float bf2f(unsigned short h){
  return __builtin_bit_cast(float, (uint32_t)h << 16);
}
__device__ __forceinline__ float tanh_fast(float x){
  float e = __expf(2.f * x);
  return (e - 1.f) * __builtin_amdgcn_rcpf(e + 1.f);
}
__device__ __forceinline__ uint32_t cvtpk(float a, float b){
  uint32_t r;
  asm("v_cvt_pk_bf16_f32 %0, %1, %2" : "=v"(r) : "v"(a), "v"(b));
  return r;
}

#define MFMA(a,b,c) __builtin_amdgcn_mfma_f32_16x16x32_bf16((a),(b),(c),0,0,0)
#define SWZ(row) (((row) & 7) << 4)

// ---------- prep: W1, Wa1 -> bf16 in ws; zero bag accumulators ----------
__global__ void prep_kernel(const float* __restrict__ W1, const float* __restrict__ Wa1,
                            unsigned short* __restrict__ w1b, unsigned short* __restrict__ wa1b,
                            float* __restrict__ bagAcc){
  int id = blockIdx.x * 256 + threadIdx.x;
  if (id < F_DIM*IN_DIM) {
    w1b[id] = f2bf(W1[id]);
  } else if (id < F_DIM*IN_DIM + A_DIM*F_DIM) {
    int j = id - F_DIM*IN_DIM;
    wa1b[j] = f2bf(Wa1[j]);
  } else if (id < F_DIM*IN_DIM + A_DIM*F_DIM + NBAGS*257) {
    bagAcc[id - (F_DIM*IN_DIM + A_DIM*F_DIM)] = 0.f;
  }
}

// ---------- fused main ----------
// 128 rows/block, 256 threads = 4 waves; EACH WAVE OWNS 32 rows x 256 cols.
// GEMM1 K-loop (16 steps, BK=64): NO LDS, NO BARRIERS — waves fully independent.
//   A (own 32 rows) from HBM into regs, depth-2 ping-pong (aN0/aN1), loads
//   issued at step END (sched_barrier-fenced) so each spans ~2 steps.
//   B (all 256 cols of W1 bf16) streamed from L2 per wave, 2 b128 per nf.
//   acc[2][16] f32x4 = 128 VGPR; per step: 16 cvtpk + 32 B-loads + 64 MFMA.
// Epilogue per block: h -> LDS Hs[128][256] bf16 (swizzled), GEMM2 (Wa1 from
// L2), tanh+dot+softmax-partials, weighted reduce, per-bag atomics.
// LDS 70144 B: Hs 64K | sc4[128][4] @64K | evec[128] @66K+512 | Pp[2][256]
__global__ __launch_bounds__(256, 2)
void mil_main(const float* __restrict__ feat,
              const unsigned short* __restrict__ w1b,
              const float* __restrict__ b1,
              const unsigned short* __restrict__ wa1b,
              const float* __restrict__ ba1,
              const float* __restrict__ wa2,
              const float* __restrict__ ba2v,
              float* __restrict__ bagAcc)
{
  extern __shared__ char lds[];
  char* HsB  = lds;                         // [128][256] bf16, swizzled
  float* sc4  = (float*)(lds + 65536);      // [128][4]
  float* evec = (float*)(lds + 65536 + 2048);
  float* Pp   = (float*)(lds + 65536 + 2048 + 512);

  const int tid  = threadIdx.x;
  const int wid  = tid >> 6;
  const int lane = tid & 63;
  const int l15  = lane & 15;
  const int l4   = lane >> 4;
  const int bRow = blockIdx.x * ROWSB;
  const int wRow = wid * 32;                // this wave's 32 rows

  // A fragment pointers: row = bRow + wRow + mf*16 + l15, k base = l4*8
  const float* aP[2];
  #pragma unroll
  for (int mf = 0; mf < 2; ++mf)
    aP[mf] = feat + (size_t)(bRow + wRow + mf*16 + l15) * IN_DIM + l4*8;

  // B base: col = nf*16 + l15 -> w1b + (nf*16+l15)*1024 + t*64 + ksub*32 + l4*8
  const unsigned short* bQ = w1b + (size_t)l15 * IN_DIM + l4*8;

  f32x4 acc[2][16];
  #pragma unroll
  for (int i = 0; i < 2; ++i)
    #pragma unroll
    for (int j = 0; j < 16; ++j) acc[i][j] = (f32x4){0.f, 0.f, 0.f, 0.f};

  float4 aN0[2][2][2], aN1[2][2][2];   // [mf][ksub][half], fp32

#define LOADA(AN, T) do{ \
    _Pragma("unroll") \
    for (int mf_ = 0; mf_ < 2; ++mf_) \
      _Pragma("unroll") \
      for (int ks_ = 0; ks_ < 2; ++ks_){ \
        const float* p_ = aP[mf_] + (T)*64 + ks_*32; \
        AN[mf_][ks_][0] = *(const float4*)p_; \
        AN[mf_][ks_][1] = *(const float4*)(p_ + 4); \
      } \
  } while(0)

#define STEP(T, AN, TN) do{ \
    short8 af_[2][2]; \
    _Pragma("unroll") \
    for (int mf_ = 0; mf_ < 2; ++mf_) \
      _Pragma("unroll") \
      for (int ks_ = 0; ks_ < 2; ++ks_){ \
        const float* v_ = (const float*)&AN[mf_][ks_][0]; \
        i32x4 w_ = { (int)cvtpk(v_[0], v_[1]), (int)cvtpk(v_[2], v_[3]), \
                     (int)cvtpk(v_[4], v_[5]), (int)cvtpk(v_[6], v_[7]) }; \
        af_[mf_][ks_] = __builtin_bit_cast(short8, w_); \
      } \
    _Pragma("unroll") \
    for (int nf_ = 0; nf_ < 16; ++nf_){ \
      const unsigned short* bp_ = bQ + (size_t)nf_*16*IN_DIM + (T)*64; \
      short8 b0_ = *(const short8*)bp_; \
      short8 b1_ = *(const short8*)(bp_ + 32); \
      acc[0][nf_] = MFMA(af_[0][0], b0_, acc[0][nf_]); \
      acc[1][nf_] = MFMA(af_[1][0], b0_, acc[1][nf_]); \
      acc[0][nf_] = MFMA(af_[0][1], b1_, acc[0][nf_]); \
      acc[1][nf_] = MFMA(af_[1][1], b1_, acc[1][nf_]); \
    } \
    __builtin_amdgcn_sched_barrier(0); \
    if ((TN) < 16) LOADA(AN, TN); \
    __builtin_amdgcn_sched_barrier(0); \
  } while(0)

  // prologue: tiles 0,1 in flight
  LOADA(aN0, 0);
  LOADA(aN1, 1);

  // K-loop: barrier-free, wave-independent; A reload is static per parity
  for (int tt = 0; tt < 8; ++tt){
    const int t0 = tt*2, t1 = tt*2 + 1;
    STEP(t0, aN0, t0 + 2);
    STEP(t1, aN1, t1 + 2);
  }

  // -------- epilogue 1: bias + relu, h -> Hs[128][256] bf16 (swizzled) --------
  float b1v[16];
  #pragma unroll
  for (int nf = 0; nf < 16; ++nf) b1v[nf] = b1[nf*16 + l15];

  #pragma unroll
  for (int mf = 0; mf < 2; ++mf)
    #pragma unroll
    for (int nf = 0; nf < 16; ++nf)
      #pragma unroll
      for (int r = 0; r < 4; ++r){
        int row = wRow + mf*16 + l4*4 + r;
        int col = nf*16 + l15;
        float v = fmaxf(acc[mf][nf][r] + b1v[nf], 0.f);
        int by = (row*512 + col*2) ^ SWZ(row);
        *(unsigned short*)(HsB + by) = f2bf(v);
      }
  __syncthreads();

  // -------- GEMM2: a = h @ Wa1.T (M=128, N=128, K=256); wave owns 32 attn cols --------
  f32x4 acc2[8][2];
  #pragma unroll
  for (int i = 0; i < 8; ++i)
    #pragma unroll
    for (int j = 0; j < 2; ++j) acc2[i][j] = (f32x4){0.f, 0.f, 0.f, 0.f};

  #pragma unroll
  for (int ks2 = 0; ks2 < 8; ++ks2){
    short8 hf[8], wf[2];
    #pragma unroll
    for (int mf = 0; mf < 8; ++mf){
      int row = mf*16 + l15;
      int by  = (row*512 + (ks2*32 + l4*8)*2) ^ SWZ(row);
      hf[mf] = *(const short8*)(HsB + by);
    }
    #pragma unroll
    for (int nf = 0; nf < 2; ++nf){
      int col = wid*32 + nf*16 + l15;
      wf[nf] = *(const short8*)(const void*)(wa1b + col*256 + ks2*32 + l4*8);
    }
    #pragma unroll
    for (int mf = 0; mf < 8; ++mf)
      #pragma unroll
      for (int nf = 0; nf < 2; ++nf)
        acc2[mf][nf] = MFMA(hf[mf], wf[nf], acc2[mf][nf]);
  }

  // -------- scores: tanh, dot Wa2, reduce across 16-lane col groups --------
  float ba1v[2], wa2v[2];
  #pragma unroll
  for (int nf = 0; nf < 2; ++nf){
    int col = wid*32 + nf*16 + l15;
    ba1v[nf] = ba1[col];
    wa2v[nf] = wa2[col];
  }
  #pragma unroll
  for (int mf = 0; mf < 8; ++mf)
    #pragma unroll
    for (int r = 0; r < 4; ++r){
      float p = tanh_fast(acc2[mf][0][r] + ba1v[0]) * wa2v[0]
              + tanh_fast(acc2[mf][1][r] + ba1v[1]) * wa2v[1];
      p += __shfl_xor(p, 1);
      p += __shfl_xor(p, 2);
      p += __shfl_xor(p, 4);
      p += __shfl_xor(p, 8);
      if (l15 == 0){
        int row = mf*16 + l4*4 + r;
        sc4[row*4 + wid] = p;
      }
    }
  __syncthreads();

  if (tid < 128){
    float s = sc4[tid*4+0] + sc4[tid*4+1] + sc4[tid*4+2] + sc4[tid*4+3] + ba2v[0];
    evec[tid] = __expf(s);   // |s| <= ~2.2 (tanh-bounded) — no max-subtraction needed
  }
  __syncthreads();

  // -------- weighted partial reduce: P[f] = sum_r e[r]*h[r][f] --------
  {
    const int f0 = (tid & 127) << 1;   // 2 features per thread
    const int g  = tid >> 7;           // 2 row groups of 64
    float p0 = 0.f, p1 = 0.f;
    const int rbase = g << 6;
    #pragma unroll 8
    for (int i = 0; i < 64; ++i){
      const int r = rbase + i;
      const uint32_t hw = *(const uint32_t*)(HsB + ((r*512 + f0*2) ^ SWZ(r)));
      const float e = evec[r];
      p0 = fmaf(e, bf2f((unsigned short)(hw & 0xffffu)), p0);
      p1 = fmaf(e, bf2f((unsigned short)(hw >> 16)),     p1);
    }
    Pp[(g << 8) + f0]     = p0;
    Pp[(g << 8) + f0 + 1] = p1;
  }
  __syncthreads();

  const int bag = bRow >> 13;   // 8192 rows per bag
  {
    float s = Pp[tid] + Pp[256 + tid];
    atomicAdd(&bagAcc[bag*257 + tid], s);
  }
  if (tid < 64){
    float se = evec[tid] + evec[tid + 64];
    se += __shfl_xor(se, 1);
    se += __shfl_xor(se, 2);
    se += __shfl_xor(se, 4);
    se += __shfl_xor(se, 8);
    se += __shfl_xor(se, 16);
    se += __shfl_xor(se, 32);
    if (tid == 0) atomicAdd(&bagAcc[bag*257 + 256], se);
  }
#undef LOADA
#undef STEP
}

// ---------- head: out[b,d] = (P[b]/E[b]) . Wh[d] + bh[d] ----------
__global__ void head_kernel(const float* __restrict__ bagAcc,
                            const float* __restrict__ wh,
                            const float* __restrict__ bh,
                            float* __restrict__ out){
  int t = threadIdx.x;          // 64 threads: b = t>>1, d = t&1
  int b = t >> 1, d = t & 1;
  const float* P = bagAcc + b*257;
  float invE = 1.f / P[256];
  float acc = 0.f;
  for (int f = 0; f < 256; ++f) acc += P[f] * wh[d*256 + f];
  out[b*2 + d] = acc * invE + bh[d];
}

extern "C" void kernel_launch(void* const* d_in, const int* in_sizes, int n_in,
                              void* d_out, int out_size, void* d_ws, size_t ws_size,
                              hipStream_t stream){
  const float* feat = (const float*)d_in[0];
  const float* W1   = (const float*)d_in[1];
  const float* b1   = (const float*)d_in[2];
  const float* Wa1  = (const float*)d_in[3];
  const float* ba1  = (const float*)d_in[4];
  const float* Wa2  = (const float*)d_in[5];
  const float* ba2  = (const float*)d_in[6];
  const float* Wh   = (const float*)d_in[7];
  const float* bh   = (const float*)d_in[8];
  // d_in[9]: bag_sizes — uniform 8192 (N_PATCHES/N_BAGS), bags contiguous.

  unsigned short* w1b  = (unsigned short*)d_ws;                        // 512 KB
  unsigned short* wa1b = (unsigned short*)((char*)d_ws + 524288);      // 64 KB
  float* bagAcc        = (float*)((char*)d_ws + 589824);               // 32*257 f32

  prep_kernel<<<1185, 256, 0, stream>>>(W1, Wa1, w1b, wa1b, bagAcc);

  const size_t ldsBytes = 65536 + 2048 + 512 + 2048;   // 70144
  mil_main<<<NBLK, 256, ldsBytes, stream>>>(feat, w1b, b1, wa1b, ba1,
                                            Wa2, ba2, bagAcc);

  head_kernel<<<1, 64, 0, stream>>>(bagAcc, Wh, bh, (float*)d_out);
}

// Round 8
// 337.438 us; speedup vs baseline: 1.9402x; 1.9402x over previous
//
#include <hip/hip_runtime.h>
#include <cstdint>
#include <cstddef>

typedef short short8 __attribute__((ext_vector_type(8)));
typedef float f32x4 __attribute__((ext_vector_type(4)));
typedef int   i32x4 __attribute__((ext_vector_type(4)));

#define NPATCH 262144
#define NBAGS  32
#define IN_DIM 1024
#define F_DIM  256
#define A_DIM  128
#define ROWSB  128
#define NBLK   (NPATCH / ROWSB)    // 2048

__device__ __forceinline__ unsigned short f2bf(float f){
  uint32_t u = __builtin_bit_cast(uint32_t, f);
  u += 0x7fffu + ((u >> 16) & 1u);
  return (unsigned short)(u >> 16);
}
__device__ __forceinline__ float bf2f(unsigned short h){
  return __builtin_bit_cast(float, (uint32_t)h << 16);
}
__device__ __forceinline__ float tanh_fast(float x){
  float e = __expf(2.f * x);
  return (e - 1.f) * __builtin_amdgcn_rcpf(e + 1.f);
}
__device__ __forceinline__ uint32_t cvtpk(float a, float b){
  uint32_t r;
  asm("v_cvt_pk_bf16_f32 %0, %1, %2" : "=v"(r) : "v"(a), "v"(b));
  return r;
}
__device__ __forceinline__ void gload_lds16(const void* g, void* l){
  __builtin_amdgcn_global_load_lds((const __attribute__((address_space(1))) void*)g,
                                   (__attribute__((address_space(3))) void*)l, 16, 0, 0);
}

#define MFMA(a,b,c) __builtin_amdgcn_mfma_f32_16x16x32_bf16((a),(b),(c),0,0,0)
// swizzles: 64B-row tiles (A/B stage, BK=32 bf16) use bits 4-5; Hs 512B rows bits 4-6
#define SWZ4(r)  (((r) & 3) << 4)
#define SWZH(r)  (((r) & 7) << 4)

// ---------- prep: W1, Wa1 -> bf16 in ws; zero bag accumulators ----------
__global__ void prep_kernel(const float* __restrict__ W1, const float* __restrict__ Wa1,
                            unsigned short* __restrict__ w1b, unsigned short* __restrict__ wa1b,
                            float* __restrict__ bagAcc){
  int id = blockIdx.x * 256 + threadIdx.x;
  if (id < F_DIM*IN_DIM) {
    w1b[id] = f2bf(W1[id]);
  } else if (id < F_DIM*IN_DIM + A_DIM*F_DIM) {
    int j = id - F_DIM*IN_DIM;
    wa1b[j] = f2bf(Wa1[j]);
  } else if (id < F_DIM*IN_DIM + A_DIM*F_DIM + NBAGS*257) {
    bagAcc[id - (F_DIM*IN_DIM + A_DIM*F_DIM)] = 0.f;
  }
}

// ---------- fused main ----------
// 128 rows/block, 256 threads, 4 waves = 2M(64 rows) x 2N(128 cols).
// GEMM1: 32 K-steps of BK=32, BOTH A and B double-buffered, ONE barrier/step:
//   step t: stage B(t+1) (gload_lds, L2 bursts) -> load A(t+2) fp32 -> regs
//           -> compute from LDS (Abuf[t&1], Bbuf[t&1])
//           -> cvt+ds_write A(t+1) (regs loaded at t-1)
//           -> s_waitcnt vmcnt(4) lgkmcnt(0) + RAW s_barrier
//   vmcnt(4) retires B(t+1); A(t+2) stays in flight ACROSS the barrier.
// B is read from L2 once per block-step (burst), fragments come from LDS ->
// VMEM port traffic = A 1.07GB (HBM) + B 1.07GB (L2 bursts), ~0.5x round 5.
// LDS 70144 B: Abuf0/1 [128][32]bf16 @0/8K | Bbuf0/1 [256][32]bf16 @16K/32K |
//   Hs [128][256] bf16 overlays [0,64K) | sc4 @64K | evec | Pp
__global__ __launch_bounds__(256, 2)
void mil_main(const float* __restrict__ feat,
              const unsigned short* __restrict__ w1b,
              const float* __restrict__ b1,
              const unsigned short* __restrict__ wa1b,
              const float* __restrict__ ba1,
              const float* __restrict__ wa2,
              const float* __restrict__ ba2v,
              float* __restrict__ bagAcc)
{
  extern __shared__ char lds[];
  char* Abuf[2] = { lds, lds + 8192 };
  char* Bbuf[2] = { lds + 16384, lds + 32768 };
  char* HsB  = lds;
  float* sc4  = (float*)(lds + 65536);
  float* evec = (float*)(lds + 65536 + 2048);
  float* Pp   = (float*)(lds + 65536 + 2048 + 512);

  const int tid  = threadIdx.x;
  const int wid  = tid >> 6;
  const int lane = tid & 63;
  const int l15  = lane & 15;
  const int l4   = lane >> 4;
  const int wm   = wid >> 1;          // 0..1: row half (64 rows)
  const int wn   = wid & 1;           // 0..1: col half (128 cols)
  const int bRow = blockIdx.x * ROWSB;

  // ---- A load (HBM, fp32): thread covers row tid>>1, k-half (tid&1)*16 ----
  const int arow = tid >> 1;
  const int ahalf = tid & 1;
  const float* aG = feat + (size_t)(bRow + arow) * IN_DIM + ahalf * 16;
  // A ds_write: 2x16B at (arow*64 + ahalf*32 + j*16) ^ SWZ4(arow)
  const int awb = arow * 64 + ahalf * 32;
  const int aswz = SWZ4(arow);

  // ---- B stage (gload): wave wid stages cols [64*wid, 64*wid+64) ----
  // linear dest Blin = wid*4096 + i*1024 + lane*16; col = Blin>>6, kb = Blin&63
  // source pre-swizzled: w1b_byte[col*2048 + t*64 + (kb ^ SWZ4(col))]
  const char* srcB[4];
  #pragma unroll
  for (int i = 0; i < 4; ++i){
    int Blin = wid*4096 + i*1024 + lane*16;
    int col  = Blin >> 6;
    int kb   = Blin & 63;
    srcB[i] = (const char*)w1b + (size_t)col*2048 + (kb ^ SWZ4(col));
  }

#define STAGEB(bb, t) do { \
    _Pragma("unroll") \
    for (int i_ = 0; i_ < 4; ++i_) \
      gload_lds16(srcB[i_] + (size_t)(t)*64, (bb) + wid*4096 + i_*1024); \
  } while(0)

#define LOADT(R, t) do { \
    const float* p_ = aG + (t)*32; \
    R[0] = *(const float4*)(p_ + 0);  R[1] = *(const float4*)(p_ + 4); \
    R[2] = *(const float4*)(p_ + 8);  R[3] = *(const float4*)(p_ + 12); \
  } while(0)

#define CVTST(R, ab) do { \
    const float* v_ = (const float*)(R); \
    i32x4 w0_ = { (int)cvtpk(v_[0],  v_[1]),  (int)cvtpk(v_[2],  v_[3]), \
                  (int)cvtpk(v_[4],  v_[5]),  (int)cvtpk(v_[6],  v_[7]) }; \
    i32x4 w1_ = { (int)cvtpk(v_[8],  v_[9]),  (int)cvtpk(v_[10], v_[11]), \
                  (int)cvtpk(v_[12], v_[13]), (int)cvtpk(v_[14], v_[15]) }; \
    *(i32x4*)((ab) + ((awb +  0) ^ aswz)) = w0_; \
    *(i32x4*)((ab) + ((awb + 16) ^ aswz)) = w1_; \
  } while(0)

#define COMPUTE(ab, bb) do { \
    short8 af_[4], bf_[8]; \
    _Pragma("unroll") \
    for (int mf_ = 0; mf_ < 4; ++mf_){ \
      int row_ = wm*64 + mf_*16 + l15; \
      af_[mf_] = *(const short8*)((ab) + (row_*64 + ((l4*16) ^ SWZ4(row_)))); \
    } \
    _Pragma("unroll") \
    for (int nf_ = 0; nf_ < 8; ++nf_){ \
      int col_ = wn*128 + nf_*16 + l15; \
      bf_[nf_] = *(const short8*)((bb) + (col_*64 + ((l4*16) ^ SWZ4(col_)))); \
    } \
    _Pragma("unroll") \
    for (int mf_ = 0; mf_ < 4; ++mf_) \
      _Pragma("unroll") \
      for (int nf_ = 0; nf_ < 8; ++nf_) \
        acc[mf_][nf_] = MFMA(af_[mf_], bf_[nf_], acc[mf_][nf_]); \
  } while(0)

#define KBAR(N) do { \
    asm volatile("s_waitcnt vmcnt(" #N ") lgkmcnt(0)" ::: "memory"); \
    __builtin_amdgcn_sched_barrier(0); \
    __builtin_amdgcn_s_barrier(); \
  } while(0)

  f32x4 acc[4][8];
  #pragma unroll
  for (int i = 0; i < 4; ++i)
    #pragma unroll
    for (int j = 0; j < 8; ++j) acc[i][j] = (f32x4){0.f, 0.f, 0.f, 0.f};

  float4 aR0[4], aR1[4];

  // ---- prologue: B(0)->Bbuf0; A(0),A(1)->regs; A(0)->Abuf0; full drain ----
  STAGEB(Bbuf[0], 0);
  LOADT(aR0, 0);
  LOADT(aR1, 1);
  CVTST(aR0, Abuf[0]);
  KBAR(0);

  // ---- steady steps t=0..29 (15 pairs), KBAR(4) each ----
  for (int tp = 0; tp < 15; ++tp){
    const int t0 = tp*2, t1 = tp*2 + 1;
    // even step t0: bufs[0]; stage B(t0+1)->Bbuf1; load A(t0+2)->aR0; cvt aR1->Abuf1
    STAGEB(Bbuf[1], t0 + 1);
    LOADT(aR0, t0 + 2);
    __builtin_amdgcn_sched_barrier(0);
    COMPUTE(Abuf[0], Bbuf[0]);
    CVTST(aR1, Abuf[1]);
    KBAR(4);
    // odd step t1: bufs[1]; stage B(t1+1)->Bbuf0; load A(t1+2)->aR1; cvt aR0->Abuf0
    STAGEB(Bbuf[0], t1 + 1);
    if (t1 + 2 < 32) LOADT(aR1, t1 + 2);
    __builtin_amdgcn_sched_barrier(0);
    COMPUTE(Abuf[1], Bbuf[1]);
    CVTST(aR0, Abuf[0]);
    KBAR(4);
  }
  // ---- t=30 (even): stage B(31)->Bbuf1; no A load; cvt aR1->Abuf1; drain ----
  STAGEB(Bbuf[1], 31);
  COMPUTE(Abuf[0], Bbuf[0]);
  CVTST(aR1, Abuf[1]);
  KBAR(0);
  // ---- t=31 (odd): compute only ----
  COMPUTE(Abuf[1], Bbuf[1]);
  __syncthreads();

  // -------- epilogue 1: bias + relu, h -> Hs[128][256] bf16 (swizzled) --------
  float b1v[8];
  #pragma unroll
  for (int nf = 0; nf < 8; ++nf) b1v[nf] = b1[wn*128 + nf*16 + l15];

  #pragma unroll
  for (int mf = 0; mf < 4; ++mf)
    #pragma unroll
    for (int nf = 0; nf < 8; ++nf)
      #pragma unroll
      for (int r = 0; r < 4; ++r){
        int row = wm*64 + mf*16 + l4*4 + r;
        int col = wn*128 + nf*16 + l15;
        float v = fmaxf(acc[mf][nf][r] + b1v[nf], 0.f);
        int by = (row*512 + col*2) ^ SWZH(row);
        *(unsigned short*)(HsB + by) = f2bf(v);
      }
  __syncthreads();

  // -------- GEMM2: a = h @ Wa1.T (M=128, N=128, K=256); wave owns 32 attn cols --------
  f32x4 acc2[8][2];
  #pragma unroll
  for (int i = 0; i < 8; ++i)
    #pragma unroll
    for (int j = 0; j < 2; ++j) acc2[i][j] = (f32x4){0.f, 0.f, 0.f, 0.f};

  #pragma unroll
  for (int ks2 = 0; ks2 < 8; ++ks2){
    short8 hf[8], wf[2];
    #pragma unroll
    for (int mf = 0; mf < 8; ++mf){
      int row = mf*16 + l15;
      int by  = (row*512 + (ks2*32 + l4*8)*2) ^ SWZH(row);
      hf[mf] = *(const short8*)(HsB + by);
    }
    #pragma unroll
    for (int nf = 0; nf < 2; ++nf){
      int col = wid*32 + nf*16 + l15;
      wf[nf] = *(const short8*)(const void*)(wa1b + col*256 + ks2*32 + l4*8);
    }
    #pragma unroll
    for (int mf = 0; mf < 8; ++mf)
      #pragma unroll
      for (int nf = 0; nf < 2; ++nf)
        acc2[mf][nf] = MFMA(hf[mf], wf[nf], acc2[mf][nf]);
  }

  // -------- scores: tanh, dot Wa2, reduce across 16-lane col groups --------
  float ba1v[2], wa2v[2];
  #pragma unroll
  for (int nf = 0; nf < 2; ++nf){
    int col = wid*32 + nf*16 + l15;
    ba1v[nf] = ba1[col];
    wa2v[nf] = wa2[col];
  }
  #pragma unroll
  for (int mf = 0; mf < 8; ++mf)
    #pragma unroll
    for (int r = 0; r < 4; ++r){
      float p = tanh_fast(acc2[mf][0][r] + ba1v[0]) * wa2v[0]
              + tanh_fast(acc2[mf][1][r] + ba1v[1]) * wa2v[1];
      p += __shfl_xor(p, 1);
      p += __shfl_xor(p, 2);
      p += __shfl_xor(p, 4);
      p += __shfl_xor(p, 8);
      if (l15 == 0){
        int row = mf*16 + l4*4 + r;
        sc4[row*4 + wid] = p;
      }
    }
  __syncthreads();

  if (tid < 128){
    float s = sc4[tid*4+0] + sc4[tid*4+1] + sc4[tid*4+2] + sc4[tid*4+3] + ba2v[0];
    evec[tid] = __expf(s);   // |s| <= ~2.2 (tanh-bounded) — no max-subtraction needed
  }
  __syncthreads();

  // -------- weighted partial reduce: P[f] = sum_r e[r]*h[r][f] --------
  {
    const int f0 = (tid & 127) << 1;
    const int g  = tid >> 7;           // 2 row groups of 64
    float p0 = 0.f, p1 = 0.f;
    const int rbase = g << 6;
    #pragma unroll 8
    for (int i = 0; i < 64; ++i){
      const int r = rbase + i;
      const uint32_t hw = *(const uint32_t*)(HsB + ((r*512 + f0*2) ^ SWZH(r)));
      const float e = evec[r];
      p0 = fmaf(e, bf2f((unsigned short)(hw & 0xffffu)), p0);
      p1 = fmaf(e, bf2f((unsigned short)(hw >> 16)),     p1);
    }
    Pp[(g << 8) + f0]     = p0;
    Pp[(g << 8) + f0 + 1] = p1;
  }
  __syncthreads();

  const int bag = bRow >> 13;   // 8192 rows per bag
  {
    float s = Pp[tid] + Pp[256 + tid];
    atomicAdd(&bagAcc[bag*257 + tid], s);
  }
  if (tid < 64){
    float se = evec[tid] + evec[tid + 64];
    se += __shfl_xor(se, 1);
    se += __shfl_xor(se, 2);
    se += __shfl_xor(se, 4);
    se += __shfl_xor(se, 8);
    se += __shfl_xor(se, 16);
    se += __shfl_xor(se, 32);
    if (tid == 0) atomicAdd(&bagAcc[bag*257 + 256], se);
  }
#undef STAGEB
#undef LOADT
#undef CVTST
#undef COMPUTE
#undef KBAR
}

// ---------- head: out[b,d] = (P[b]/E[b]) . Wh[d] + bh[d] ----------
__global__ void head_kernel(const float* __restrict__ bagAcc,
                            const float* __restrict__ wh,
                            const float* __restrict__ bh,
                            float* __restrict__ out){
  int t = threadIdx.x;          // 64 threads: b = t>>1, d = t&1
  int b = t >> 1, d = t & 1;
  const float* P = bagAcc + b*257;
  float invE = 1.f / P[256];
  float acc = 0.f;
  for (int f = 0; f < 256; ++f) acc += P[f] * wh[d*256 + f];
  out[b*2 + d] = acc * invE + bh[d];
}

extern "C" void kernel_launch(void* const* d_in, const int* in_sizes, int n_in,
                              void* d_out, int out_size, void* d_ws, size_t ws_size,
                              hipStream_t stream){
  const float* feat = (const float*)d_in[0];
  const float* W1   = (const float*)d_in[1];
  const float* b1   = (const float*)d_in[2];
  const float* Wa1  = (const float*)d_in[3];
  const float* ba1  = (const float*)d_in[4];
  const float* Wa2  = (const float*)d_in[5];
  const float* ba2  = (const float*)d_in[6];
  const float* Wh   = (const float*)d_in[7];
  const float* bh   = (const float*)d_in[8];
  // d_in[9]: bag_sizes — uniform 8192 (N_PATCHES/N_BAGS), bags contiguous.

  unsigned short* w1b  = (unsigned short*)d_ws;                        // 512 KB
  unsigned short* wa1b = (unsigned short*)((char*)d_ws + 524288);      // 64 KB
  float* bagAcc        = (float*)((char*)d_ws + 589824);               // 32*257 f32

  prep_kernel<<<1185, 256, 0, stream>>>(W1, Wa1, w1b, wa1b, bagAcc);

  const size_t ldsBytes = 65536 + 2048 + 512 + 2048;   // 70144
  mil_main<<<NBLK, 256, ldsBytes, stream>>>(feat, w1b, b1, wa1b, ba1,
                                            Wa2, ba2, bagAcc);

  head_kernel<<<1, 64, 0, stream>>>(bagAcc, Wh, bh, (float*)d_out);
}